// Round 3
// baseline (812.430 us; speedup 1.0000x reference)
//
#include <hip/hip_runtime.h>
#include <cmath>

// Problem constants (from reference setup_inputs)
#define IN_PN   20000
#define OUT_PN  5000
#define MM      9
#define CIN     32
#define COUT    64
#define OUT_STRIDE 68   // 64 + 4 pad for the epilogue transpose

typedef short        bf16x8 __attribute__((ext_vector_type(8)));
typedef float        f32x16 __attribute__((ext_vector_type(16)));
typedef unsigned int u32x4  __attribute__((ext_vector_type(4)));

// Pack [bf16(x1) : bf16(x0)] by truncation (RTZ). The lo-part of the split
// captures the truncation remainder exactly (x - trunc(x) is exact in fp32).
__device__ __forceinline__ unsigned pack_bf16_hi(float x0, float x1) {
    return __builtin_amdgcn_perm(__float_as_uint(x1), __float_as_uint(x0), 0x07060302u);
}
__device__ __forceinline__ float bf16_trunc(float x) {
    return __uint_as_float(__float_as_uint(x) & 0xFFFF0000u);
}
__device__ __forceinline__ bf16x8 frag(u32x4 u) { return __builtin_bit_cast(bf16x8, u); }

// Split 8 fp32 (two float4) into hi/lo bf16 fragments (4 VGPRs each).
__device__ __forceinline__ void split_pair(float4 u, float4 v, u32x4& hi, u32x4& lo) {
    hi[0] = pack_bf16_hi(u.x, u.y);
    hi[1] = pack_bf16_hi(u.z, u.w);
    hi[2] = pack_bf16_hi(v.x, v.y);
    hi[3] = pack_bf16_hi(v.z, v.w);
    lo[0] = pack_bf16_hi(u.x - bf16_trunc(u.x), u.y - bf16_trunc(u.y));
    lo[1] = pack_bf16_hi(u.z - bf16_trunc(u.z), u.w - bf16_trunc(u.w));
    lo[2] = pack_bf16_hi(v.x - bf16_trunc(v.x), v.y - bf16_trunc(v.y));
    lo[3] = pack_bf16_hi(v.z - bf16_trunc(v.z), v.w - bf16_trunc(v.w));
}
__device__ __forceinline__ float uniform_f(float x) {
    return __uint_as_float(__builtin_amdgcn_readfirstlane(__float_as_uint(x)));
}

// One block per output point p; 4 waves; wave (wr,wc) owns C tile [wr*32..][wc*32..].
// C(64x64) = X(64x288) . W(288x64) via v_mfma_f32_32x32x16_bf16, 3-product hi/lo
// split (fp32-grade precision). No LDS in the main loop; explicit 1-deep software
// pipeline: m+1's A/B global loads are issued before m's convert+MFMA phase so the
// compute covers the memory latency (compiler alone scheduled loads just-in-time:
// round-2 VGPR=64, VALUBusy 18%).
//   A-fragment (32x32x16): row = lane%32, k = (lane/32)*8 + e
//   B-fragment:            col = lane%32, k = (lane/32)*8 + e
//   C/D (HW-verified):     col = lane&31, row = (reg&3) + 8*(reg>>2) + 4*(lane>>5)
// Residual path: rva accumulates p_m-weighted X in fp32 during the A loads; its
// register layout IS the A-fragment of the 64x32x64 GEMM against weight_res.
// Epilogue: LDS transpose + float4 stores (direct dword stores measured 5.3x HBM
// write amplification: 425 MB vs 80 MB for this pattern — round-2 counter evidence).
__global__ __launch_bounds__(256, 4) void pconv_kernel(
    const float* __restrict__ in_pc,       // (B, IN_PN, CIN)
    const int*   __restrict__ neighbor_id, // (OUT_PN, M)
    const float* __restrict__ weights,     // (OUT_PN, M, COUT, CIN)
    const float* __restrict__ bias,        // (OUT_PN, COUT)
    const float* __restrict__ p_neighbors, // (OUT_PN, M)
    const float* __restrict__ weight_res,  // (COUT, CIN)
    float*       __restrict__ out)         // (B, OUT_PN, COUT)
{
    __shared__ float smem[64 * OUT_STRIDE];   // 17408 B, epilogue transpose only
    const int p    = blockIdx.x;
    const int t    = threadIdx.x;
    const int lane = t & 63;
    const int wv   = t >> 6;
    const int wr   = wv >> 1;        // b-half of C
    const int wc   = wv & 1;         // o-half of C
    const int l32  = lane & 31;
    const int lh   = lane >> 5;      // k-chunk selector

    // ---- block-uniform neighbor ids + normalized residual weights (SGPRs) ----
    int   nid[MM];
    float pn[MM];
    float psum = 0.f;
#pragma unroll
    for (int m = 0; m < MM; ++m) {
        nid[m] = __builtin_amdgcn_readfirstlane(neighbor_id[p * MM + m]);
        float pv = fabsf(p_neighbors[p * MM + m]);
        pv = (nid[m] != IN_PN) ? pv : 0.f;
        pn[m] = pv;
        psum += pv;
    }
    const float pinv = 1.f / (psum + 1e-8f);
#pragma unroll
    for (int m = 0; m < MM; ++m) pn[m] = uniform_f(pn[m] * pinv);

    const int brow = wr * 32 + l32;       // A row (batch)
    const int ocol = wc * 32 + l32;       // B col (output channel)

    const float* Abase = in_pc      + (size_t)brow * (IN_PN * CIN) + lh * 8;
    const float* Bbase = weights    + (size_t)p * (MM * COUT * CIN) + (size_t)ocol * CIN + lh * 8;
    const float* wrb   = weight_res + (size_t)ocol * CIN + lh * 8;

    float4 Abuf[2][4], Bbuf[2][4];
    const float4 zero4 = make_float4(0.f, 0.f, 0.f, 0.f);

#define LOADA(buf_, m_) do {                                           \
        const int n_ = nid[m_];                                        \
        if (n_ != IN_PN) {                                             \
            const float* a_ = Abase + (size_t)n_ * CIN;                \
            Abuf[buf_][0] = *(const float4*)(a_);                      \
            Abuf[buf_][1] = *(const float4*)(a_ + 4);                  \
            Abuf[buf_][2] = *(const float4*)(a_ + 16);                 \
            Abuf[buf_][3] = *(const float4*)(a_ + 20);                 \
        } else {                                                       \
            Abuf[buf_][0] = zero4; Abuf[buf_][1] = zero4;              \
            Abuf[buf_][2] = zero4; Abuf[buf_][3] = zero4;              \
        }                                                              \
    } while (0)
#define LOADB(buf_, m_) do {                                           \
        const float* b_ = Bbase + (m_) * (COUT * CIN);                 \
        Bbuf[buf_][0] = *(const float4*)(b_);                          \
        Bbuf[buf_][1] = *(const float4*)(b_ + 4);                      \
        Bbuf[buf_][2] = *(const float4*)(b_ + 16);                     \
        Bbuf[buf_][3] = *(const float4*)(b_ + 20);                     \
    } while (0)

    f32x16 accC;
#pragma unroll
    for (int j = 0; j < 16; ++j) accC[j] = 0.f;
    float4 rva[4];
#pragma unroll
    for (int i = 0; i < 4; ++i) rva[i] = zero4;

    float bv = 0.f;
    LOADA(0, 0);
    LOADB(0, 0);

    // ---- main loop: 1-deep pipelined, 9 m-steps x 2 K-substeps x 3 split-MFMAs
#pragma unroll
    for (int m = 0; m < MM; ++m) {
        const int cur = m & 1;
        const int nxt = cur ^ 1;
        if (m + 1 < MM) {
            LOADA(nxt, m + 1);
            LOADB(nxt, m + 1);
        } else {
            // free prefetch slot: epilogue operands into the dead B buffer
            Bbuf[nxt][0] = *(const float4*)(wrb);
            Bbuf[nxt][1] = *(const float4*)(wrb + 4);
            Bbuf[nxt][2] = *(const float4*)(wrb + 16);
            Bbuf[nxt][3] = *(const float4*)(wrb + 20);
            bv = bias[p * COUT + ocol];
        }

        // residual accumulation rides for free on the fp32 A registers
        const float pm = pn[m];
#pragma unroll
        for (int i = 0; i < 4; ++i) {
            rva[i].x += pm * Abuf[cur][i].x;
            rva[i].y += pm * Abuf[cur][i].y;
            rva[i].z += pm * Abuf[cur][i].z;
            rva[i].w += pm * Abuf[cur][i].w;
        }

        u32x4 ah, al, bh, bl;
        split_pair(Abuf[cur][0], Abuf[cur][1], ah, al);
        split_pair(Bbuf[cur][0], Bbuf[cur][1], bh, bl);
        accC = __builtin_amdgcn_mfma_f32_32x32x16_bf16(frag(ah), frag(bh), accC, 0, 0, 0);
        accC = __builtin_amdgcn_mfma_f32_32x32x16_bf16(frag(ah), frag(bl), accC, 0, 0, 0);
        accC = __builtin_amdgcn_mfma_f32_32x32x16_bf16(frag(al), frag(bh), accC, 0, 0, 0);
        split_pair(Abuf[cur][2], Abuf[cur][3], ah, al);
        split_pair(Bbuf[cur][2], Bbuf[cur][3], bh, bl);
        accC = __builtin_amdgcn_mfma_f32_32x32x16_bf16(frag(ah), frag(bh), accC, 0, 0, 0);
        accC = __builtin_amdgcn_mfma_f32_32x32x16_bf16(frag(ah), frag(bl), accC, 0, 0, 0);
        accC = __builtin_amdgcn_mfma_f32_32x32x16_bf16(frag(al), frag(bh), accC, 0, 0, 0);
    }
#undef LOADA
#undef LOADB

    // ---- residual GEMM: R(64x32) . weight_res^T(32x64); Wres sits in Bbuf[1] ----
    f32x16 accR;
#pragma unroll
    for (int j = 0; j < 16; ++j) accR[j] = 0.f;
    {
        u32x4 ah, al, bh, bl;
        split_pair(rva[0], rva[1], ah, al);
        split_pair(Bbuf[1][0], Bbuf[1][1], bh, bl);
        accR = __builtin_amdgcn_mfma_f32_32x32x16_bf16(frag(ah), frag(bh), accR, 0, 0, 0);
        accR = __builtin_amdgcn_mfma_f32_32x32x16_bf16(frag(ah), frag(bl), accR, 0, 0, 0);
        accR = __builtin_amdgcn_mfma_f32_32x32x16_bf16(frag(al), frag(bh), accR, 0, 0, 0);
        split_pair(rva[2], rva[3], ah, al);
        split_pair(Bbuf[1][2], Bbuf[1][3], bh, bl);
        accR = __builtin_amdgcn_mfma_f32_32x32x16_bf16(frag(ah), frag(bh), accR, 0, 0, 0);
        accR = __builtin_amdgcn_mfma_f32_32x32x16_bf16(frag(ah), frag(bl), accR, 0, 0, 0);
        accR = __builtin_amdgcn_mfma_f32_32x32x16_bf16(frag(al), frag(bh), accR, 0, 0, 0);
    }

    // ---- epilogue: bias + elu, combine, LDS transpose, float4 stores ----
#pragma unroll
    for (int j = 0; j < 16; ++j) {
        const int br = wr * 32 + (j & 3) + 8 * (j >> 2) + 4 * lh;
        float cv = accC[j] + bv;
        cv = (cv > 0.f) ? cv : expm1f(cv);                  // jax.nn.elu
        smem[br * OUT_STRIDE + ocol] = 0.70710678118654752f * (cv + accR[j]);
    }
    __syncthreads();

    const int bb = t >> 2;   // store: batch row
    const int q  = t & 3;    // store: quarter of a 64-float row
#pragma unroll
    for (int s = 0; s < 4; ++s) {
        float4 v = *(const float4*)&smem[bb * OUT_STRIDE + q * 16 + s * 4];
        *(float4*)&out[((size_t)bb * OUT_PN + (size_t)p) * COUT + q * 16 + s * 4] = v;
    }
}

extern "C" void kernel_launch(void* const* d_in, const int* in_sizes, int n_in,
                              void* d_out, int out_size, void* d_ws, size_t ws_size,
                              hipStream_t stream) {
    const float* in_pc       = (const float*)d_in[0];
    const int*   neighbor_id = (const int*)d_in[1];
    const float* weights     = (const float*)d_in[2];
    const float* bias        = (const float*)d_in[3];
    const float* p_neighbors = (const float*)d_in[4];
    const float* weight_res  = (const float*)d_in[5];
    float*       out         = (float*)d_out;

    pconv_kernel<<<OUT_PN, 256, 0, stream>>>(in_pc, neighbor_id, weights, bias,
                                             p_neighbors, weight_res, out);
}

// Round 5
// 671.087 us; speedup vs baseline: 1.2106x; 1.2106x over previous
//
#include <hip/hip_runtime.h>
#include <cmath>

// Problem constants (from reference setup_inputs)
#define IN_PN   20000
#define OUT_PN  5000
#define MM      9
#define CIN     32
#define COUT    64
#define OUT_STRIDE 68   // 64 + 4 pad for the epilogue transpose

typedef short        bf16x8 __attribute__((ext_vector_type(8)));
typedef float        f32x16 __attribute__((ext_vector_type(16)));
typedef unsigned int u32x4  __attribute__((ext_vector_type(4)));

// Pack [bf16(x1) : bf16(x0)] by truncation (RTZ). The lo-part of the split
// captures the truncation remainder exactly (x - trunc(x) is exact in fp32).
__device__ __forceinline__ unsigned pack_bf16_hi(float x0, float x1) {
    return __builtin_amdgcn_perm(__float_as_uint(x1), __float_as_uint(x0), 0x07060302u);
}
__device__ __forceinline__ float bf16_trunc(float x) {
    return __uint_as_float(__float_as_uint(x) & 0xFFFF0000u);
}
__device__ __forceinline__ bf16x8 frag(u32x4 u) { return __builtin_bit_cast(bf16x8, u); }

// Split 8 fp32 (two float4) into hi/lo bf16 fragments (4 VGPRs each).
__device__ __forceinline__ void split_pair(float4 u, float4 v, u32x4& hi, u32x4& lo) {
    hi[0] = pack_bf16_hi(u.x, u.y);
    hi[1] = pack_bf16_hi(u.z, u.w);
    hi[2] = pack_bf16_hi(v.x, v.y);
    hi[3] = pack_bf16_hi(v.z, v.w);
    lo[0] = pack_bf16_hi(u.x - bf16_trunc(u.x), u.y - bf16_trunc(u.y));
    lo[1] = pack_bf16_hi(u.z - bf16_trunc(u.z), u.w - bf16_trunc(u.w));
    lo[2] = pack_bf16_hi(v.x - bf16_trunc(v.x), v.y - bf16_trunc(v.y));
    lo[3] = pack_bf16_hi(v.z - bf16_trunc(v.z), v.w - bf16_trunc(v.w));
}
__device__ __forceinline__ float uniform_f(float x) {
    return __uint_as_float(__builtin_amdgcn_readfirstlane(__float_as_uint(x)));
}

// One block per output point p; 4 waves; wave (wr,wc) owns C tile [wr*32..][wc*32..].
// C(64x64) = X(64x288) . W(288x64) via v_mfma_f32_32x32x16_bf16, 3-product hi/lo
// split (fp32-grade precision). Explicit 1-deep register pipeline for A/B.
//
// Round-3 lesson (counter evidence): with __launch_bounds__(256,4) the allocator
// landed at 64 VGPR and spilled the pipeline buffers to scratch; scratch lines
// thrashed L2 and evicted to HBM (WRITE_SIZE 533 MB vs the 80 MB output).
// Fix: __launch_bounds__(256,2) raises the VGPR cap to 256 so everything stays
// in registers, and a single sched_barrier(0) per m-step stops the scheduler
// from sinking the prefetch loads back to just-in-time (HIP-compiler behavior).
//   A-fragment (32x32x16): row = lane%32, k = (lane/32)*8 + e
//   B-fragment:            col = lane%32, k = (lane/32)*8 + e
//   C/D (HW-verified):     col = lane&31, row = (reg&3) + 8*(reg>>2) + 4*(lane>>5)
// Residual path: rva accumulates p_m-weighted X in fp32 during the A loads; its
// register layout IS the A-fragment of the 64x32x64 GEMM against weight_res.
__global__ __launch_bounds__(256, 2) void pconv_kernel(
    const float* __restrict__ in_pc,       // (B, IN_PN, CIN)
    const int*   __restrict__ neighbor_id, // (OUT_PN, M)
    const float* __restrict__ weights,     // (OUT_PN, M, COUT, CIN)
    const float* __restrict__ bias,        // (OUT_PN, COUT)
    const float* __restrict__ p_neighbors, // (OUT_PN, M)
    const float* __restrict__ weight_res,  // (COUT, CIN)
    float*       __restrict__ out)         // (B, OUT_PN, COUT)
{
    __shared__ float smem[64 * OUT_STRIDE];   // 17408 B, epilogue transpose only
    const int p    = blockIdx.x;
    const int t    = threadIdx.x;
    const int lane = t & 63;
    const int wv   = t >> 6;
    const int wr   = wv >> 1;        // b-half of C
    const int wc   = wv & 1;         // o-half of C
    const int l32  = lane & 31;
    const int lh   = lane >> 5;      // k-chunk selector

    // ---- block-uniform neighbor ids + normalized residual weights (SGPRs) ----
    int   nid[MM];
    float pn[MM];
    float psum = 0.f;
#pragma unroll
    for (int m = 0; m < MM; ++m) {
        nid[m] = __builtin_amdgcn_readfirstlane(neighbor_id[p * MM + m]);
        float pv = fabsf(p_neighbors[p * MM + m]);
        pv = (nid[m] != IN_PN) ? pv : 0.f;
        pn[m] = pv;
        psum += pv;
    }
    const float pinv = 1.f / (psum + 1e-8f);
#pragma unroll
    for (int m = 0; m < MM; ++m) pn[m] = uniform_f(pn[m] * pinv);

    const int brow = wr * 32 + l32;       // A row (batch)
    const int ocol = wc * 32 + l32;       // B col (output channel)

    const float* Abase = in_pc      + (size_t)brow * (IN_PN * CIN) + lh * 8;
    const float* Bbase = weights    + (size_t)p * (MM * COUT * CIN) + (size_t)ocol * CIN + lh * 8;
    const float* wrb   = weight_res + (size_t)ocol * CIN + lh * 8;

    float4 Abuf[2][4], Bbuf[2][4];
    const float4 zero4 = make_float4(0.f, 0.f, 0.f, 0.f);

#define LOADA(buf_, m_) do {                                           \
        const int n_ = nid[m_];                                        \
        if (n_ != IN_PN) {                                             \
            const float* a_ = Abase + (size_t)n_ * CIN;                \
            Abuf[buf_][0] = *(const float4*)(a_);                      \
            Abuf[buf_][1] = *(const float4*)(a_ + 4);                  \
            Abuf[buf_][2] = *(const float4*)(a_ + 16);                 \
            Abuf[buf_][3] = *(const float4*)(a_ + 20);                 \
        } else {                                                       \
            Abuf[buf_][0] = zero4; Abuf[buf_][1] = zero4;              \
            Abuf[buf_][2] = zero4; Abuf[buf_][3] = zero4;              \
        }                                                              \
    } while (0)
#define LOADB(buf_, m_) do {                                           \
        const float* b_ = Bbase + (m_) * (COUT * CIN);                 \
        Bbuf[buf_][0] = *(const float4*)(b_);                          \
        Bbuf[buf_][1] = *(const float4*)(b_ + 4);                      \
        Bbuf[buf_][2] = *(const float4*)(b_ + 16);                     \
        Bbuf[buf_][3] = *(const float4*)(b_ + 20);                     \
    } while (0)

    f32x16 accC;
#pragma unroll
    for (int j = 0; j < 16; ++j) accC[j] = 0.f;
    float4 rva[4];
#pragma unroll
    for (int i = 0; i < 4; ++i) rva[i] = zero4;

    float bv = 0.f;
    LOADA(0, 0);
    LOADB(0, 0);

    // ---- main loop: 1-deep pipelined, 9 m-steps x 2 K-substeps x 3 split-MFMAs
#pragma unroll
    for (int m = 0; m < MM; ++m) {
        const int cur = m & 1;
        const int nxt = cur ^ 1;
        if (m + 1 < MM) {
            LOADA(nxt, m + 1);
            LOADB(nxt, m + 1);
        } else {
            // free prefetch slot: epilogue operands into the dead B buffer
            Bbuf[nxt][0] = *(const float4*)(wrb);
            Bbuf[nxt][1] = *(const float4*)(wrb + 4);
            Bbuf[nxt][2] = *(const float4*)(wrb + 16);
            Bbuf[nxt][3] = *(const float4*)(wrb + 20);
            bv = bias[p * COUT + ocol];
        }
        // Pin: prefetch loads issued above may not sink below this point.
        __builtin_amdgcn_sched_barrier(0);

        // residual accumulation rides for free on the fp32 A registers
        const float pm = pn[m];
#pragma unroll
        for (int i = 0; i < 4; ++i) {
            rva[i].x += pm * Abuf[cur][i].x;
            rva[i].y += pm * Abuf[cur][i].y;
            rva[i].z += pm * Abuf[cur][i].z;
            rva[i].w += pm * Abuf[cur][i].w;
        }

        u32x4 ah, al, bh, bl;
        split_pair(Abuf[cur][0], Abuf[cur][1], ah, al);
        split_pair(Bbuf[cur][0], Bbuf[cur][1], bh, bl);
        accC = __builtin_amdgcn_mfma_f32_32x32x16_bf16(frag(ah), frag(bh), accC, 0, 0, 0);
        accC = __builtin_amdgcn_mfma_f32_32x32x16_bf16(frag(ah), frag(bl), accC, 0, 0, 0);
        accC = __builtin_amdgcn_mfma_f32_32x32x16_bf16(frag(al), frag(bh), accC, 0, 0, 0);
        split_pair(Abuf[cur][2], Abuf[cur][3], ah, al);
        split_pair(Bbuf[cur][2], Bbuf[cur][3], bh, bl);
        accC = __builtin_amdgcn_mfma_f32_32x32x16_bf16(frag(ah), frag(bh), accC, 0, 0, 0);
        accC = __builtin_amdgcn_mfma_f32_32x32x16_bf16(frag(ah), frag(bl), accC, 0, 0, 0);
        accC = __builtin_amdgcn_mfma_f32_32x32x16_bf16(frag(al), frag(bh), accC, 0, 0, 0);
    }
#undef LOADA
#undef LOADB

    // ---- residual GEMM: R(64x32) . weight_res^T(32x64); Wres sits in Bbuf[1] ----
    f32x16 accR;
#pragma unroll
    for (int j = 0; j < 16; ++j) accR[j] = 0.f;
    {
        u32x4 ah, al, bh, bl;
        split_pair(rva[0], rva[1], ah, al);
        split_pair(Bbuf[1][0], Bbuf[1][1], bh, bl);
        accR = __builtin_amdgcn_mfma_f32_32x32x16_bf16(frag(ah), frag(bh), accR, 0, 0, 0);
        accR = __builtin_amdgcn_mfma_f32_32x32x16_bf16(frag(ah), frag(bl), accR, 0, 0, 0);
        accR = __builtin_amdgcn_mfma_f32_32x32x16_bf16(frag(al), frag(bh), accR, 0, 0, 0);
        split_pair(rva[2], rva[3], ah, al);
        split_pair(Bbuf[1][2], Bbuf[1][3], bh, bl);
        accR = __builtin_amdgcn_mfma_f32_32x32x16_bf16(frag(ah), frag(bh), accR, 0, 0, 0);
        accR = __builtin_amdgcn_mfma_f32_32x32x16_bf16(frag(ah), frag(bl), accR, 0, 0, 0);
        accR = __builtin_amdgcn_mfma_f32_32x32x16_bf16(frag(al), frag(bh), accR, 0, 0, 0);
    }

    // ---- epilogue: bias + elu, combine, LDS transpose, float4 stores ----
#pragma unroll
    for (int j = 0; j < 16; ++j) {
        const int br = wr * 32 + (j & 3) + 8 * (j >> 2) + 4 * lh;
        float cv = accC[j] + bv;
        cv = (cv > 0.f) ? cv : expm1f(cv);                  // jax.nn.elu
        smem[br * OUT_STRIDE + ocol] = 0.70710678118654752f * (cv + accR[j]);
    }
    __syncthreads();

    const int bb = t >> 2;   // store: batch row
    const int q  = t & 3;    // store: quarter of a 64-float row
#pragma unroll
    for (int s = 0; s < 4; ++s) {
        float4 v = *(const float4*)&smem[bb * OUT_STRIDE + q * 16 + s * 4];
        *(float4*)&out[((size_t)bb * OUT_PN + (size_t)p) * COUT + q * 16 + s * 4] = v;
    }
}

extern "C" void kernel_launch(void* const* d_in, const int* in_sizes, int n_in,
                              void* d_out, int out_size, void* d_ws, size_t ws_size,
                              hipStream_t stream) {
    const float* in_pc       = (const float*)d_in[0];
    const int*   neighbor_id = (const int*)d_in[1];
    const float* weights     = (const float*)d_in[2];
    const float* bias        = (const float*)d_in[3];
    const float* p_neighbors = (const float*)d_in[4];
    const float* weight_res  = (const float*)d_in[5];
    float*       out         = (float*)d_out;

    pconv_kernel<<<OUT_PN, 256, 0, stream>>>(in_pc, neighbor_id, weights, bias,
                                             p_neighbors, weight_res, out);
}